// Round 7
// baseline (134.835 us; speedup 1.0000x reference)
//
#include <hip/hip_runtime.h>
#include <hip/hip_bf16.h>
#include <stdint.h>
#include <stddef.h>

// MHA fwd: B=2 S=2048 D=1024 H=16 DK=64.
// wt (W->Wt bf16 transpose) -> gemm_qkv (fp32-A staged via global_load_lds,
// in-reg cvt; m97 barrier structure) -> flash (1024 blocks x 128 threads:
// 2 waves x 32 q-rows each, KVBLK=64 double-buffered 32KB LDS -> 4 sync
// domains/CU) -> gemm_o (64x128).
//
// R7: flash wall analysis: 61us/32 iters = ~4500 cyc/iter vs ~600 active ->
// 75% stalled; R5 proved intra-block pipelining null; only 2 barrier-coupled
// blocks/CU. Repackage WITHOUT changing per-wave work (R4's mistake was
// halving it): 2-wave blocks over 64 q-rows, grid 1024, 32KB LDS ->
// 4 independent sync domains per CU. Reverted R6's QKT-hoist (62.7 vs 61.3).
// gemm_qkv/gemm_o unchanged from R6.

typedef __bf16 bf16;
typedef __attribute__((ext_vector_type(4))) bf16 bf16x4;
typedef __attribute__((ext_vector_type(8))) bf16 bf16x8;
typedef __attribute__((ext_vector_type(4))) float f32x4;
typedef __attribute__((ext_vector_type(16))) float f32x16;
typedef __attribute__((ext_vector_type(2))) unsigned int uint2v;

#define DEVINL static __device__ __forceinline__

DEVINL void gload_lds16(const void* g, void* l) {
  __builtin_amdgcn_global_load_lds(
      (const __attribute__((address_space(1))) void*)g,
      (__attribute__((address_space(3))) void*)l, 16, 0, 0);
}

DEVINL f32x4 mfma16(bf16x8 a, bf16x8 b, f32x4 c) {
  return __builtin_amdgcn_mfma_f32_16x16x32_bf16(a, b, c, 0, 0, 0);
}
DEVINL f32x16 mfma32(bf16x8 a, bf16x8 b, f32x16 c) {
  return __builtin_amdgcn_mfma_f32_32x32x16_bf16(a, b, c, 0, 0, 0);
}
// v_exp_f32 computes 2^x; log2(e) is folded into the Q pre-scale.
DEVINL float fexp2(float x) {
  float r;
  asm("v_exp_f32 %0, %1" : "=v"(r) : "v"(x));
  return r;
}
// RNE f32->bf16 pair pack via compiler casts (m240: don't hand-write cvt_pk).
DEVINL unsigned pack2(float lo, float hi) {
  union { bf16 h[2]; unsigned u; } t;
  t.h[0] = (bf16)lo; t.h[1] = (bf16)hi;
  return t.u;
}
DEVINL bf16x8 mk8(unsigned a, unsigned b, unsigned c, unsigned d) {
  union { unsigned u[4]; bf16x8 v; } t;
  t.u[0] = a; t.u[1] = b; t.u[2] = c; t.u[3] = d;
  return t.v;
}

// ---------------------------------------------------------------------------
// Kernel 1: weight transpose+convert. W[k][n] fp32 -> Wt[t][n][k] bf16
// ---------------------------------------------------------------------------
__global__ __launch_bounds__(256) void wt_kernel(
    const float* __restrict__ w0, const float* __restrict__ w1,
    const float* __restrict__ w2, const float* __restrict__ w3,
    bf16* __restrict__ out) {
  __shared__ float tile[64 * 65];
  int t = blockIdx.y;
  const float* w = (t == 0) ? w0 : (t == 1) ? w1 : (t == 2) ? w2 : w3;
  bf16* o = out + (size_t)t * 1024 * 1024;
  int tb = blockIdx.x;
  int k0 = (tb >> 4) * 64, n0 = (tb & 15) * 64;
  int c = threadIdx.x & 63, r0 = threadIdx.x >> 6;
  for (int r = r0; r < 64; r += 4)
    tile[r * 65 + c] = w[(size_t)(k0 + r) * 1024 + n0 + c];
  __syncthreads();
  for (int r = r0; r < 64; r += 4)
    o[(size_t)(n0 + r) * 1024 + k0 + c] = (bf16)tile[c * 65 + r];
}

// ---------------------------------------------------------------------------
// Kernel 2: QKV projection GEMM. A = fp32 input staged via global_load_lds
// into swizzled fp32 LDS tile (8 chunks/row, chunk ^= row&7), converted to
// bf16 fragments in-register after ds_read. B = bf16 Wt.
// Q scaled by 0.125*log2e in epilogue -> Qp; K -> Kp; V transposed -> Vt.
// ---------------------------------------------------------------------------
__global__ __launch_bounds__(256) void gemm_qkv(
    const float* __restrict__ Aq, const float* __restrict__ Ak,
    const float* __restrict__ Av, const bf16* __restrict__ Wt,
    const float* __restrict__ bq, const float* __restrict__ bk,
    const float* __restrict__ bv,
    bf16* __restrict__ outQ, bf16* __restrict__ outK, bf16* __restrict__ Vt) {
  int z = blockIdx.z;
  const float* A   = (z == 0) ? Aq : (z == 1) ? Ak : Av;
  const bf16* Wz   = Wt + (size_t)z * 1024 * 1024;
  const float* bia = (z == 0) ? bq : (z == 1) ? bk : bv;
  float scale      = (z == 0) ? 0.18033688011112042f : 1.0f;  // 0.125*log2(e)

  __shared__ float Af[2][128 * 32];   // fp32 A tile, 16KB each
  __shared__ bf16  Bs[2][128 * 32];   // bf16 B tile, 8KB each

  int m0 = blockIdx.x * 128, n0 = blockIdx.y * 128;
  int tid = threadIdx.x, w = tid >> 6, l = tid & 63;
  int wm = (w >> 1) * 64, wn = (w & 1) * 64;
  int c16 = l & 15, g = l >> 4;
  int rsw = (c16 >> 1) & 3;           // B read-side swizzle

  // A staging: 1024 16B-units; unit u: row=u>>3, phys chunk=u&7,
  // logical source chunk = (u&7)^(row&7). 4 units/thread.
  int ua[4], arow[4], asrc[4];
#pragma unroll
  for (int i = 0; i < 4; ++i) {
    ua[i] = (w * 4 + i) * 64 + l;
    arow[i] = ua[i] >> 3;
    asrc[i] = ((ua[i] & 7) ^ (arow[i] & 7)) * 4;  // float offset within row
  }
  // B staging: 2 units/thread, pre-swizzled global k-chunk
  int brow0 = (w * 2 + 0) * 16 + (l >> 2);
  int brow1 = (w * 2 + 1) * 16 + (l >> 2);
  int bk0 = ((l & 3) ^ ((brow0 >> 1) & 3)) * 8;
  int bk1 = ((l & 3) ^ ((brow1 >> 1) & 3)) * 8;

  f32x4 acc[4][4] = {};

#define STAGE_QKV(buf, kt)                                                   \
  do {                                                                       \
    _Pragma("unroll") for (int i = 0; i < 4; ++i)                            \
      gload_lds16(A + (size_t)(m0 + arow[i]) * 1024 + (kt) + asrc[i],        \
                  (char*)Af[buf] + ua[i] * 16);                              \
    gload_lds16(Wz + (size_t)(n0 + brow0) * 1024 + (kt) + bk0,               \
                (char*)Bs[buf] + (w * 2 + 0) * 1024 + l * 16);               \
    gload_lds16(Wz + (size_t)(n0 + brow1) * 1024 + (kt) + bk1,               \
                (char*)Bs[buf] + (w * 2 + 1) * 1024 + l * 16);               \
  } while (0)

  STAGE_QKV(0, 0);
  __syncthreads();

  int cur = 0;
  for (int kt = 0; kt < 1024; kt += 32) {
    if (kt < 992) STAGE_QKV(cur ^ 1, kt + 32);
    bf16x8 af[4], bfr[4];
#pragma unroll
    for (int mt = 0; mt < 4; ++mt) {
      int row = wm + mt * 16 + c16;
      int r7 = row & 7;
      f32x4 lo = *(const f32x4*)&Af[cur][row * 32 + (((2 * g)     ^ r7) << 2)];
      f32x4 hi = *(const f32x4*)&Af[cur][row * 32 + (((2 * g + 1) ^ r7) << 2)];
      bf16x8 h;
#pragma unroll
      for (int j = 0; j < 4; ++j) { h[j] = (bf16)lo[j]; h[4 + j] = (bf16)hi[j]; }
      af[mt] = h;
    }
#pragma unroll
    for (int nt = 0; nt < 4; ++nt)
      bfr[nt] = *(const bf16x8*)&Bs[cur][(wn + nt * 16 + c16) * 32 + ((g ^ rsw) * 8)];
#pragma unroll
    for (int mt = 0; mt < 4; ++mt)
#pragma unroll
      for (int nt = 0; nt < 4; ++nt)
        acc[mt][nt] = mfma16(af[mt], bfr[nt], acc[mt][nt]);
    __syncthreads();  // drains vmcnt -> next buffer staged
    cur ^= 1;
  }
#undef STAGE_QKV

  if (z < 2) {
    bf16* Cout = (z == 0) ? outQ : outK;
#pragma unroll
    for (int mt = 0; mt < 4; ++mt)
#pragma unroll
      for (int nt = 0; nt < 4; ++nt) {
        int n = n0 + wn + nt * 16 + c16;
        float bb = bia[n];
#pragma unroll
        for (int r = 0; r < 4; ++r) {
          int m = m0 + wm + mt * 16 + g * 4 + r;
          Cout[(size_t)m * 1024 + n] = (bf16)((acc[mt][nt][r] + bb) * scale);
        }
      }
  } else {
    // V: write transposed -> Vt[(b*16+h)*64 + dk][s], 4 consecutive s per lane
#pragma unroll
    for (int mt = 0; mt < 4; ++mt)
#pragma unroll
      for (int nt = 0; nt < 4; ++nt) {
        int n = n0 + wn + nt * 16 + c16;       // h*64 + dk
        float bb = bia[n];
        int m = m0 + wm + mt * 16 + g * 4;     // b*2048 + s (4-aligned)
        int b = m >> 11, s = m & 2047;
        bf16x4 v;
#pragma unroll
        for (int r = 0; r < 4; ++r) v[r] = (bf16)(acc[mt][nt][r] + bb);
        *(bf16x4*)&Vt[((size_t)(b * 16 + (n >> 6)) * 64 + (n & 63)) * 2048 + s] = v;
      }
  }
}

// ---------------------------------------------------------------------------
// Kernel 3: flash attention. Block = (b,h,64 q-rows); 2 waves x 32 q-rows,
// each wave processes the FULL KVBLK=64 (same per-wave work as R3).
// K [s][dk] / Vt [dk][s] double-buffered in 32KB LDS, XOR-swizzled.
// Grid 1024 -> 4 blocks/CU = 4 independent sync domains.
// Swapped QK^T (mfma32(K,Q)) -> P lane-local -> pack+permlane32_swap -> PV.
// Softmax uses 2^x directly (log2e folded into Q scale upstream).
// ---------------------------------------------------------------------------
__global__ __launch_bounds__(128) void flash_kernel(
    const bf16* __restrict__ Qp, const bf16* __restrict__ Kp,
    const bf16* __restrict__ Vt, bf16* __restrict__ AO) {
  __shared__ __align__(16) bf16 Ks[2][64 * 64];
  __shared__ __align__(16) bf16 Vs[2][64 * 64];

  int orig = blockIdx.x;
  int wg = (orig & 7) * 128 + (orig >> 3);  // XCD-chunked, bijective (1024%8==0)
  int bh = wg >> 5, qb = wg & 31;
  int b = bh >> 4, h = bh & 15;
  int tid = threadIdx.x, w = tid >> 6, l = tid & 63;
  int lo5 = l & 31, g = l >> 5;
  int q0 = qb * 64 + w * 32;

  // Q as B-fragments: qf[kt] = Q[q0+lo5][kt*16 + g*8 + j]
  const bf16* qptr = Qp + (size_t)(b * 2048 + q0 + lo5) * 1024 + h * 64 + g * 8;
  bf16x8 qf0 = *(const bf16x8*)(qptr + 0);
  bf16x8 qf1 = *(const bf16x8*)(qptr + 16);
  bf16x8 qf2 = *(const bf16x8*)(qptr + 32);
  bf16x8 qf3 = *(const bf16x8*)(qptr + 48);

  const bf16* kbase = Kp + (size_t)(b * 2048) * 1024 + h * 64;
  const bf16* vbase = Vt + (size_t)bh * 64 * 2048;

  // staging: 512 units per tensor; unit u: row=u>>3, col c=u&7, src col c^(row&7)
  // 4 K-units + 4 V-units per thread (128 threads)
  int uu[4], rs[4], cs[4];
#pragma unroll
  for (int i = 0; i < 4; ++i) {
    uu[i] = i * 128 + tid;
    rs[i] = uu[i] >> 3;
    cs[i] = (uu[i] & 7) ^ (rs[i] & 7);
  }

#define STAGE(buf, s0)                                                          \
  do {                                                                          \
    _Pragma("unroll") for (int i = 0; i < 4; ++i)                               \
      gload_lds16(kbase + (size_t)((s0) + rs[i]) * 1024 + cs[i] * 8,            \
                  (bf16*)Ks[buf] + uu[i] * 8);                                  \
    _Pragma("unroll") for (int i = 0; i < 4; ++i)                               \
      gload_lds16(vbase + (size_t)rs[i] * 2048 + (s0) + cs[i] * 8,              \
                  (bf16*)Vs[buf] + uu[i] * 8);                                  \
  } while (0)

#define LDSK(cp, nt, kt) \
  (*(const bf16x8*)&cp[(((nt)*32 + lo5) << 6) + (((((kt)*2 + g)) ^ (lo5 & 7)) << 3)])
#define LDSV(cp, dt, st) \
  (*(const bf16x8*)&cp[(((dt)*32 + lo5) << 6) + (((((st)*2 + g)) ^ (lo5 & 7)) << 3)])

  f32x16 o0 = {}, o1 = {};
  float ps0 = 0.f, ps1 = 0.f, ps2 = 0.f, ps3 = 0.f;

  STAGE(0, 0);
  int cur = 0;
  for (int t = 0; t < 32; ++t) {
    if (t < 31) {
      STAGE(cur ^ 1, (t + 1) * 64);
      asm volatile("s_waitcnt vmcnt(8)" ::: "memory");   // tile t landed
    } else {
      asm volatile("s_waitcnt vmcnt(0)" ::: "memory");
    }
    __builtin_amdgcn_s_barrier();
    __builtin_amdgcn_sched_barrier(0);
    const bf16* kc = Ks[cur];
    const bf16* vc = Vs[cur];

    // ---- S^T tile 0 (k_local 0..31; row=k, col=q=lo5) ----
    f32x16 sv = {};
    __builtin_amdgcn_s_setprio(1);
    sv = mfma32(LDSK(kc, 0, 0), qf0, sv);
    sv = mfma32(LDSK(kc, 0, 1), qf1, sv);
    sv = mfma32(LDSK(kc, 0, 2), qf2, sv);
    sv = mfma32(LDSK(kc, 0, 3), qf3, sv);
    __builtin_amdgcn_s_setprio(0);
    float p[16];
#pragma unroll
    for (int r = 0; r < 16; ++r) p[r] = fexp2(sv[r]);
    ps0 += p[0] + p[4] + p[8] + p[12];
    ps1 += p[1] + p[5] + p[9] + p[13];
    ps2 += p[2] + p[6] + p[10] + p[14];
    ps3 += p[3] + p[7] + p[11] + p[15];
    unsigned pw0 = pack2(p[0], p[1]), pw1 = pack2(p[2], p[3]);
    unsigned pw2 = pack2(p[4], p[5]), pw3 = pack2(p[6], p[7]);
    unsigned pw4 = pack2(p[8], p[9]), pw5 = pack2(p[10], p[11]);
    unsigned pw6 = pack2(p[12], p[13]), pw7 = pack2(p[14], p[15]);
    uint2v a02 = __builtin_amdgcn_permlane32_swap(pw0, pw2, false, false);
    uint2v a13 = __builtin_amdgcn_permlane32_swap(pw1, pw3, false, false);
    uint2v a46 = __builtin_amdgcn_permlane32_swap(pw4, pw6, false, false);
    uint2v a57 = __builtin_amdgcn_permlane32_swap(pw5, pw7, false, false);
    bf16x8 pa0 = mk8(a02.x, a13.x, a02.y, a13.y);  // s 0..15
    bf16x8 pa1 = mk8(a46.x, a57.x, a46.y, a57.y);  // s 16..31

    // ---- S^T tile 1 (k_local 32..63) ----
    f32x16 sw = {};
    __builtin_amdgcn_s_setprio(1);
    sw = mfma32(LDSK(kc, 1, 0), qf0, sw);
    sw = mfma32(LDSK(kc, 1, 1), qf1, sw);
    sw = mfma32(LDSK(kc, 1, 2), qf2, sw);
    sw = mfma32(LDSK(kc, 1, 3), qf3, sw);
    __builtin_amdgcn_s_setprio(0);
#pragma unroll
    for (int r = 0; r < 16; ++r) p[r] = fexp2(sw[r]);
    ps0 += p[0] + p[4] + p[8] + p[12];
    ps1 += p[1] + p[5] + p[9] + p[13];
    ps2 += p[2] + p[6] + p[10] + p[14];
    ps3 += p[3] + p[7] + p[11] + p[15];
    pw0 = pack2(p[0], p[1]); pw1 = pack2(p[2], p[3]);
    pw2 = pack2(p[4], p[5]); pw3 = pack2(p[6], p[7]);
    pw4 = pack2(p[8], p[9]); pw5 = pack2(p[10], p[11]);
    pw6 = pack2(p[12], p[13]); pw7 = pack2(p[14], p[15]);
    a02 = __builtin_amdgcn_permlane32_swap(pw0, pw2, false, false);
    a13 = __builtin_amdgcn_permlane32_swap(pw1, pw3, false, false);
    a46 = __builtin_amdgcn_permlane32_swap(pw4, pw6, false, false);
    a57 = __builtin_amdgcn_permlane32_swap(pw5, pw7, false, false);
    bf16x8 pb0 = mk8(a02.x, a13.x, a02.y, a13.y);  // s 32..47
    bf16x8 pb1 = mk8(a46.x, a57.x, a46.y, a57.y);  // s 48..63

    // ---- O += P V ----
    __builtin_amdgcn_s_setprio(1);
    o0 = mfma32(pa0, LDSV(vc, 0, 0), o0);
    o1 = mfma32(pa0, LDSV(vc, 1, 0), o1);
    o0 = mfma32(pa1, LDSV(vc, 0, 1), o0);
    o1 = mfma32(pa1, LDSV(vc, 1, 1), o1);
    o0 = mfma32(pb0, LDSV(vc, 0, 2), o0);
    o1 = mfma32(pb0, LDSV(vc, 1, 2), o1);
    o0 = mfma32(pb1, LDSV(vc, 0, 3), o0);
    o1 = mfma32(pb1, LDSV(vc, 1, 3), o1);
    __builtin_amdgcn_s_setprio(0);

    __builtin_amdgcn_sched_barrier(0);
    __builtin_amdgcn_s_barrier();
    cur ^= 1;
  }
#undef STAGE
#undef LDSK
#undef LDSV

  // tot on lane l = softmax denominator for q = q0 + (l&31)
  float plsum = (ps0 + ps1) + (ps2 + ps3);
  float tot = plsum + __shfl_xor(plsum, 32);

#pragma unroll
  for (int r = 0; r < 16; ++r) {
    int qr = (r & 3) + 8 * (r >> 2) + 4 * g;        // output row of o0[r]/o1[r]
    float inv = 1.0f / __shfl(tot, qr);             // row qr's denominator
    bf16* op = AO + (size_t)(b * 2048 + q0 + qr) * 1024 + h * 64 + lo5;
    op[0]  = (bf16)(o0[r] * inv);
    op[32] = (bf16)(o1[r] * inv);
  }
}

// ---------------------------------------------------------------------------
// Kernel 4: output projection, 64x128 tile (512 blocks = 2/CU), m97 structure,
// swizzled LDS. fp32 out + bias.
// ---------------------------------------------------------------------------
__global__ __launch_bounds__(256) void gemm_o(
    const bf16* __restrict__ A, const bf16* __restrict__ Wt3,
    const float* __restrict__ bo, float* __restrict__ C) {
  __shared__ bf16 As[2][64 * 32];
  __shared__ bf16 Bs[2][128 * 32];
  int m0 = blockIdx.x * 64, n0 = blockIdx.y * 128;
  int tid = threadIdx.x, w = tid >> 6, l = tid & 63;
  int wm = (w >> 1) * 32, wn = (w & 1) * 64;
  int c16 = l & 15, g = l >> 4;
  int rsw = (c16 >> 1) & 3;

  // A staging: 1 chunk/lane. row = tid>>2, phys chunk = tid&3
  int arow = tid >> 2, akc = tid & 3;
  int asrc = (akc ^ ((arow >> 1) & 3)) * 8;
  // B staging: 2 chunks/lane
  int brow0 = (w * 2 + 0) * 16 + (l >> 2);
  int brow1 = (w * 2 + 1) * 16 + (l >> 2);
  int bk0 = ((l & 3) ^ ((brow0 >> 1) & 3)) * 8;
  int bk1 = ((l & 3) ^ ((brow1 >> 1) & 3)) * 8;

  f32x4 acc[2][4] = {};

#define STAGE_O(buf, kt)                                                     \
  do {                                                                       \
    gload_lds16(A + (size_t)(m0 + arow) * 1024 + (kt) + asrc,                \
                (char*)As[buf] + tid * 16);                                  \
    gload_lds16(Wt3 + (size_t)(n0 + brow0) * 1024 + (kt) + bk0,              \
                (char*)Bs[buf] + (w * 2 + 0) * 1024 + l * 16);               \
    gload_lds16(Wt3 + (size_t)(n0 + brow1) * 1024 + (kt) + bk1,              \
                (char*)Bs[buf] + (w * 2 + 1) * 1024 + l * 16);               \
  } while (0)

  STAGE_O(0, 0);
  __syncthreads();

  int cur = 0;
  for (int kt = 0; kt < 1024; kt += 32) {
    if (kt < 992) STAGE_O(cur ^ 1, kt + 32);
    bf16x8 af[2], bfr[4];
#pragma unroll
    for (int mt = 0; mt < 2; ++mt)
      af[mt] = *(const bf16x8*)&As[cur][(wm + mt * 16 + c16) * 32 + ((g ^ rsw) * 8)];
#pragma unroll
    for (int nt = 0; nt < 4; ++nt)
      bfr[nt] = *(const bf16x8*)&Bs[cur][(wn + nt * 16 + c16) * 32 + ((g ^ rsw) * 8)];
#pragma unroll
    for (int mt = 0; mt < 2; ++mt)
#pragma unroll
      for (int nt = 0; nt < 4; ++nt)
        acc[mt][nt] = mfma16(af[mt], bfr[nt], acc[mt][nt]);
    __syncthreads();  // drains vmcnt -> next buffer staged
    cur ^= 1;
  }
#undef STAGE_O

#pragma unroll
  for (int mt = 0; mt < 2; ++mt)
#pragma unroll
    for (int nt = 0; nt < 4; ++nt) {
      int n = n0 + wn + nt * 16 + c16;
      float bb = bo[n];
#pragma unroll
      for (int r = 0; r < 4; ++r) {
        int m = m0 + wm + mt * 16 + g * 4 + r;
        C[(size_t)m * 1024 + n] = acc[mt][nt][r] + bb;
      }
    }
}

// ---------------------------------------------------------------------------
extern "C" void kernel_launch(void* const* d_in, const int* in_sizes, int n_in,
                              void* d_out, int out_size, void* d_ws, size_t ws_size,
                              hipStream_t stream) {
  const float* query = (const float*)d_in[0];
  const float* key_  = (const float*)d_in[1];
  const float* value = (const float*)d_in[2];
  const float* Wq = (const float*)d_in[3];
  const float* bq = (const float*)d_in[4];
  const float* Wk = (const float*)d_in[5];
  const float* bk = (const float*)d_in[6];
  const float* Wv = (const float*)d_in[7];
  const float* bv = (const float*)d_in[8];
  const float* Wo = (const float*)d_in[9];
  const float* bo = (const float*)d_in[10];
  float* out = (float*)d_out;

  char* ws = (char*)d_ws;
  const size_t MB = 1024 * 1024;
  bf16* Wt  = (bf16*)(ws);              // 4 x [1024][1024] bf16 = 8 MB
  bf16* Qp  = (bf16*)(ws + 8 * MB);     // [4096][1024] bf16 (pre-scaled)
  bf16* Kp  = (bf16*)(ws + 16 * MB);    // [4096][1024]
  bf16* Vt  = (bf16*)(ws + 24 * MB);    // [32][64][2048]
  bf16* AO  = (bf16*)(ws + 32 * MB);    // attn out [4096][1024]

  wt_kernel<<<dim3(256, 4), dim3(256), 0, stream>>>(Wq, Wk, Wv, Wo, Wt);
  gemm_qkv<<<dim3(32, 8, 3), dim3(256), 0, stream>>>(query, key_, value, Wt,
                                                     bq, bk, bv, Qp, Kp, Vt);
  flash_kernel<<<dim3(1024), dim3(128), 0, stream>>>(Qp, Kp, Vt, AO);
  gemm_o<<<dim3(64, 8), dim3(256), 0, stream>>>(AO, Wt + (size_t)3 * 1024 * 1024, bo, out);
}

// Round 8
// 124.550 us; speedup vs baseline: 1.0826x; 1.0826x over previous
//
#include <hip/hip_runtime.h>
#include <hip/hip_bf16.h>
#include <stdint.h>
#include <stddef.h>

// MHA fwd: B=2 S=2048 D=1024 H=16 DK=64.
// wt (W->Wt bf16) -> gemm_qkv (fp32-A staged via global_load_lds, in-reg cvt;
// m97 barrier structure) -> flash (512 blocks x 4 waves x 32 q-rows, KVBLK=64,
// quad-buffered LDS, 1 barrier/iter, S-PIPELINED: QK^T(t+1) issues alongside
// softmax(t) -> breaks per-wave serial chain) -> gemm_o (64x128).
//
// R8: R7 (more sync domains) regressed: waves/CU is structurally capped at 8
// (2048 waves total), staging doubled. Reverted to 512x256 shape. Flash's
// remaining lever (R4/R5/R6/R7 all null on staging/barriers): the per-wave
// SERIAL chain ds_read->QK->exp/pack->PV. T15-analog fix: keep TWO S-states;
// at iter t issue QK(t+1) (matrix pipe, from prefetched Ks[(t+1)&3]) before
// softmax(t) (VALU) - independent, so they overlap. vmcnt(6) after
// STAGE(t+2) guarantees V(t) and K(t+1) landed (6 newest = V(t+1)+tile(t+2)).
// VGPR +64 is free (occupancy structurally capped at 2 waves/SIMD).

typedef __bf16 bf16;
typedef __attribute__((ext_vector_type(4))) bf16 bf16x4;
typedef __attribute__((ext_vector_type(8))) bf16 bf16x8;
typedef __attribute__((ext_vector_type(4))) float f32x4;
typedef __attribute__((ext_vector_type(16))) float f32x16;
typedef __attribute__((ext_vector_type(2))) unsigned int uint2v;

#define DEVINL static __device__ __forceinline__

DEVINL void gload_lds16(const void* g, void* l) {
  __builtin_amdgcn_global_load_lds(
      (const __attribute__((address_space(1))) void*)g,
      (__attribute__((address_space(3))) void*)l, 16, 0, 0);
}

DEVINL f32x4 mfma16(bf16x8 a, bf16x8 b, f32x4 c) {
  return __builtin_amdgcn_mfma_f32_16x16x32_bf16(a, b, c, 0, 0, 0);
}
DEVINL f32x16 mfma32(bf16x8 a, bf16x8 b, f32x16 c) {
  return __builtin_amdgcn_mfma_f32_32x32x16_bf16(a, b, c, 0, 0, 0);
}
// v_exp_f32 computes 2^x; log2(e) is folded into the Q pre-scale.
DEVINL float fexp2(float x) {
  float r;
  asm("v_exp_f32 %0, %1" : "=v"(r) : "v"(x));
  return r;
}
// RNE f32->bf16 pair pack via compiler casts (m240: don't hand-write cvt_pk).
DEVINL unsigned pack2(float lo, float hi) {
  union { bf16 h[2]; unsigned u; } t;
  t.h[0] = (bf16)lo; t.h[1] = (bf16)hi;
  return t.u;
}
DEVINL bf16x8 mk8(unsigned a, unsigned b, unsigned c, unsigned d) {
  union { unsigned u[4]; bf16x8 v; } t;
  t.u[0] = a; t.u[1] = b; t.u[2] = c; t.u[3] = d;
  return t.v;
}

// ---------------------------------------------------------------------------
// Kernel 1: weight transpose+convert. W[k][n] fp32 -> Wt[t][n][k] bf16
// ---------------------------------------------------------------------------
__global__ __launch_bounds__(256) void wt_kernel(
    const float* __restrict__ w0, const float* __restrict__ w1,
    const float* __restrict__ w2, const float* __restrict__ w3,
    bf16* __restrict__ out) {
  __shared__ float tile[64 * 65];
  int t = blockIdx.y;
  const float* w = (t == 0) ? w0 : (t == 1) ? w1 : (t == 2) ? w2 : w3;
  bf16* o = out + (size_t)t * 1024 * 1024;
  int tb = blockIdx.x;
  int k0 = (tb >> 4) * 64, n0 = (tb & 15) * 64;
  int c = threadIdx.x & 63, r0 = threadIdx.x >> 6;
  for (int r = r0; r < 64; r += 4)
    tile[r * 65 + c] = w[(size_t)(k0 + r) * 1024 + n0 + c];
  __syncthreads();
  for (int r = r0; r < 64; r += 4)
    o[(size_t)(n0 + r) * 1024 + k0 + c] = (bf16)tile[c * 65 + r];
}

// ---------------------------------------------------------------------------
// Kernel 2: QKV projection GEMM. A = fp32 input staged via global_load_lds
// into swizzled fp32 LDS tile (8 chunks/row, chunk ^= row&7), converted to
// bf16 fragments in-register after ds_read. B = bf16 Wt.
// Q scaled by 0.125*log2e in epilogue -> Qp; K -> Kp; V transposed -> Vt.
// ---------------------------------------------------------------------------
__global__ __launch_bounds__(256) void gemm_qkv(
    const float* __restrict__ Aq, const float* __restrict__ Ak,
    const float* __restrict__ Av, const bf16* __restrict__ Wt,
    const float* __restrict__ bq, const float* __restrict__ bk,
    const float* __restrict__ bv,
    bf16* __restrict__ outQ, bf16* __restrict__ outK, bf16* __restrict__ Vt) {
  int z = blockIdx.z;
  const float* A   = (z == 0) ? Aq : (z == 1) ? Ak : Av;
  const bf16* Wz   = Wt + (size_t)z * 1024 * 1024;
  const float* bia = (z == 0) ? bq : (z == 1) ? bk : bv;
  float scale      = (z == 0) ? 0.18033688011112042f : 1.0f;  // 0.125*log2(e)

  __shared__ float Af[2][128 * 32];   // fp32 A tile, 16KB each
  __shared__ bf16  Bs[2][128 * 32];   // bf16 B tile, 8KB each

  int m0 = blockIdx.x * 128, n0 = blockIdx.y * 128;
  int tid = threadIdx.x, w = tid >> 6, l = tid & 63;
  int wm = (w >> 1) * 64, wn = (w & 1) * 64;
  int c16 = l & 15, g = l >> 4;
  int rsw = (c16 >> 1) & 3;           // B read-side swizzle

  // A staging: 1024 16B-units; unit u: row=u>>3, phys chunk=u&7,
  // logical source chunk = (u&7)^(row&7). 4 units/thread.
  int ua[4], arow[4], asrc[4];
#pragma unroll
  for (int i = 0; i < 4; ++i) {
    ua[i] = (w * 4 + i) * 64 + l;
    arow[i] = ua[i] >> 3;
    asrc[i] = ((ua[i] & 7) ^ (arow[i] & 7)) * 4;  // float offset within row
  }
  // B staging: 2 units/thread, pre-swizzled global k-chunk
  int brow0 = (w * 2 + 0) * 16 + (l >> 2);
  int brow1 = (w * 2 + 1) * 16 + (l >> 2);
  int bk0 = ((l & 3) ^ ((brow0 >> 1) & 3)) * 8;
  int bk1 = ((l & 3) ^ ((brow1 >> 1) & 3)) * 8;

  f32x4 acc[4][4] = {};

#define STAGE_QKV(buf, kt)                                                   \
  do {                                                                       \
    _Pragma("unroll") for (int i = 0; i < 4; ++i)                            \
      gload_lds16(A + (size_t)(m0 + arow[i]) * 1024 + (kt) + asrc[i],        \
                  (char*)Af[buf] + ua[i] * 16);                              \
    gload_lds16(Wz + (size_t)(n0 + brow0) * 1024 + (kt) + bk0,               \
                (char*)Bs[buf] + (w * 2 + 0) * 1024 + l * 16);               \
    gload_lds16(Wz + (size_t)(n0 + brow1) * 1024 + (kt) + bk1,               \
                (char*)Bs[buf] + (w * 2 + 1) * 1024 + l * 16);               \
  } while (0)

  STAGE_QKV(0, 0);
  __syncthreads();

  int cur = 0;
  for (int kt = 0; kt < 1024; kt += 32) {
    if (kt < 992) STAGE_QKV(cur ^ 1, kt + 32);
    bf16x8 af[4], bfr[4];
#pragma unroll
    for (int mt = 0; mt < 4; ++mt) {
      int row = wm + mt * 16 + c16;
      int r7 = row & 7;
      f32x4 lo = *(const f32x4*)&Af[cur][row * 32 + (((2 * g)     ^ r7) << 2)];
      f32x4 hi = *(const f32x4*)&Af[cur][row * 32 + (((2 * g + 1) ^ r7) << 2)];
      bf16x8 h;
#pragma unroll
      for (int j = 0; j < 4; ++j) { h[j] = (bf16)lo[j]; h[4 + j] = (bf16)hi[j]; }
      af[mt] = h;
    }
#pragma unroll
    for (int nt = 0; nt < 4; ++nt)
      bfr[nt] = *(const bf16x8*)&Bs[cur][(wn + nt * 16 + c16) * 32 + ((g ^ rsw) * 8)];
#pragma unroll
    for (int mt = 0; mt < 4; ++mt)
#pragma unroll
      for (int nt = 0; nt < 4; ++nt)
        acc[mt][nt] = mfma16(af[mt], bfr[nt], acc[mt][nt]);
    __syncthreads();  // drains vmcnt -> next buffer staged
    cur ^= 1;
  }
#undef STAGE_QKV

  if (z < 2) {
    bf16* Cout = (z == 0) ? outQ : outK;
#pragma unroll
    for (int mt = 0; mt < 4; ++mt)
#pragma unroll
      for (int nt = 0; nt < 4; ++nt) {
        int n = n0 + wn + nt * 16 + c16;
        float bb = bia[n];
#pragma unroll
        for (int r = 0; r < 4; ++r) {
          int m = m0 + wm + mt * 16 + g * 4 + r;
          Cout[(size_t)m * 1024 + n] = (bf16)((acc[mt][nt][r] + bb) * scale);
        }
      }
  } else {
    // V: write transposed -> Vt[(b*16+h)*64 + dk][s], 4 consecutive s per lane
#pragma unroll
    for (int mt = 0; mt < 4; ++mt)
#pragma unroll
      for (int nt = 0; nt < 4; ++nt) {
        int n = n0 + wn + nt * 16 + c16;       // h*64 + dk
        float bb = bia[n];
        int m = m0 + wm + mt * 16 + g * 4;     // b*2048 + s (4-aligned)
        int b = m >> 11, s = m & 2047;
        bf16x4 v;
#pragma unroll
        for (int r = 0; r < 4; ++r) v[r] = (bf16)(acc[mt][nt][r] + bb);
        *(bf16x4*)&Vt[((size_t)(b * 16 + (n >> 6)) * 64 + (n & 63)) * 2048 + s] = v;
      }
  }
}

// ---------------------------------------------------------------------------
// Kernel 3: flash attention, S-pipelined. Block = (b,h,128 q-rows);
// 4 waves x 32 q-rows. KVBLK=64, quad-buffered LDS (K [s][dk], Vt [dk][s]),
// XOR-swizzled, 1 barrier/iter, prefetch depth 2.
// Two S-states (A/B): at step t, QK^T(t+1) [matrix pipe] issues before
// softmax(t) [VALU] - independent ops overlap. PV(t) closes the step.
// Softmax uses 2^x directly (log2e folded into Q scale upstream).
// ---------------------------------------------------------------------------
__global__ __launch_bounds__(256, 2) void flash_kernel(
    const bf16* __restrict__ Qp, const bf16* __restrict__ Kp,
    const bf16* __restrict__ Vt, bf16* __restrict__ AO) {
  __shared__ __align__(16) bf16 Ks[4][64 * 64];
  __shared__ __align__(16) bf16 Vs[4][64 * 64];

  int orig = blockIdx.x;
  int wg = (orig & 7) * 64 + (orig >> 3);   // XCD-chunked, bijective (512 % 8 == 0)
  int bh = wg >> 4, qb = wg & 15;
  int b = bh >> 4, h = bh & 15;
  int tid = threadIdx.x, w = tid >> 6, l = tid & 63;
  int lo5 = l & 31, g = l >> 5;
  int q0 = qb * 128 + w * 32;

  // Q as B-fragments: qf[kt] = Q[q0+lo5][kt*16 + g*8 + j]
  const bf16* qptr = Qp + (size_t)(b * 2048 + q0 + lo5) * 1024 + h * 64 + g * 8;
  bf16x8 qf0 = *(const bf16x8*)(qptr + 0);
  bf16x8 qf1 = *(const bf16x8*)(qptr + 16);
  bf16x8 qf2 = *(const bf16x8*)(qptr + 32);
  bf16x8 qf3 = *(const bf16x8*)(qptr + 48);

  const bf16* kbase = Kp + (size_t)(b * 2048) * 1024 + h * 64;
  const bf16* vbase = Vt + (size_t)bh * 64 * 2048;

  // staging: unit u in [0,512): row=u>>3, col unit c=u&7, source col c^(row&7)
  int u0 = w * 64 + l;
  int u1 = (4 + w) * 64 + l;
  int r0s = u0 >> 3, c0s = (u0 & 7) ^ (r0s & 7);
  int r1s = u1 >> 3, c1s = (u1 & 7) ^ (r1s & 7);

  // STAGE issue order: K,K,V,V (vmcnt counting relies on this)
#define STAGE(buf, s0)                                                          \
  do {                                                                          \
    gload_lds16(kbase + (size_t)((s0) + r0s) * 1024 + c0s * 8,                  \
                (bf16*)Ks[buf] + u0 * 8);                                       \
    gload_lds16(kbase + (size_t)((s0) + r1s) * 1024 + c1s * 8,                  \
                (bf16*)Ks[buf] + u1 * 8);                                       \
    gload_lds16(vbase + (size_t)r0s * 2048 + (s0) + c0s * 8,                    \
                (bf16*)Vs[buf] + u0 * 8);                                       \
    gload_lds16(vbase + (size_t)r1s * 2048 + (s0) + c1s * 8,                    \
                (bf16*)Vs[buf] + u1 * 8);                                       \
  } while (0)

#define LDSK(cp, nt, kt) \
  (*(const bf16x8*)&cp[(((nt)*32 + lo5) << 6) + (((((kt)*2 + g)) ^ (lo5 & 7)) << 3)])
#define LDSV(cp, dt, st) \
  (*(const bf16x8*)&cp[(((dt)*32 + lo5) << 6) + (((((st)*2 + g)) ^ (lo5 & 7)) << 3)])

#define QK(d0, d1, kc)                                                          \
  do {                                                                          \
    __builtin_amdgcn_s_setprio(1);                                              \
    d0 = z16; d1 = z16;                                                         \
    d0 = mfma32(LDSK(kc, 0, 0), qf0, d0);                                       \
    d0 = mfma32(LDSK(kc, 0, 1), qf1, d0);                                       \
    d0 = mfma32(LDSK(kc, 0, 2), qf2, d0);                                       \
    d0 = mfma32(LDSK(kc, 0, 3), qf3, d0);                                       \
    d1 = mfma32(LDSK(kc, 1, 0), qf0, d1);                                       \
    d1 = mfma32(LDSK(kc, 1, 1), qf1, d1);                                       \
    d1 = mfma32(LDSK(kc, 1, 2), qf2, d1);                                       \
    d1 = mfma32(LDSK(kc, 1, 3), qf3, d1);                                       \
    __builtin_amdgcn_s_setprio(0);                                              \
  } while (0)

#define SOFTMAX(sv, sw)                                                         \
  do {                                                                          \
    float p[16];                                                                \
    _Pragma("unroll") for (int r = 0; r < 16; ++r) p[r] = fexp2(sv[r]);         \
    ps0 += p[0] + p[4] + p[8] + p[12];                                          \
    ps1 += p[1] + p[5] + p[9] + p[13];                                          \
    ps2 += p[2] + p[6] + p[10] + p[14];                                         \
    ps3 += p[3] + p[7] + p[11] + p[15];                                         \
    unsigned pw0 = pack2(p[0], p[1]), pw1 = pack2(p[2], p[3]);                  \
    unsigned pw2 = pack2(p[4], p[5]), pw3 = pack2(p[6], p[7]);                  \
    unsigned pw4 = pack2(p[8], p[9]), pw5 = pack2(p[10], p[11]);                \
    unsigned pw6 = pack2(p[12], p[13]), pw7 = pack2(p[14], p[15]);              \
    uint2v a02 = __builtin_amdgcn_permlane32_swap(pw0, pw2, false, false);      \
    uint2v a13 = __builtin_amdgcn_permlane32_swap(pw1, pw3, false, false);      \
    uint2v a46 = __builtin_amdgcn_permlane32_swap(pw4, pw6, false, false);      \
    uint2v a57 = __builtin_amdgcn_permlane32_swap(pw5, pw7, false, false);      \
    pa0 = mk8(a02.x, a13.x, a02.y, a13.y);                                      \
    pa1 = mk8(a46.x, a57.x, a46.y, a57.y);                                      \
    _Pragma("unroll") for (int r = 0; r < 16; ++r) p[r] = fexp2(sw[r]);         \
    ps0 += p[0] + p[4] + p[8] + p[12];                                          \
    ps1 += p[1] + p[5] + p[9] + p[13];                                          \
    ps2 += p[2] + p[6] + p[10] + p[14];                                         \
    ps3 += p[3] + p[7] + p[11] + p[15];                                         \
    pw0 = pack2(p[0], p[1]); pw1 = pack2(p[2], p[3]);                           \
    pw2 = pack2(p[4], p[5]); pw3 = pack2(p[6], p[7]);                           \
    pw4 = pack2(p[8], p[9]); pw5 = pack2(p[10], p[11]);                         \
    pw6 = pack2(p[12], p[13]); pw7 = pack2(p[14], p[15]);                       \
    a02 = __builtin_amdgcn_permlane32_swap(pw0, pw2, false, false);             \
    a13 = __builtin_amdgcn_permlane32_swap(pw1, pw3, false, false);             \
    a46 = __builtin_amdgcn_permlane32_swap(pw4, pw6, false, false);             \
    a57 = __builtin_amdgcn_permlane32_swap(pw5, pw7, false, false);             \
    pb0 = mk8(a02.x, a13.x, a02.y, a13.y);                                      \
    pb1 = mk8(a46.x, a57.x, a46.y, a57.y);                                      \
  } while (0)

#define PV(vc)                                                                  \
  do {                                                                          \
    __builtin_amdgcn_s_setprio(1);                                              \
    o0 = mfma32(pa0, LDSV(vc, 0, 0), o0);                                       \
    o1 = mfma32(pa0, LDSV(vc, 1, 0), o1);                                       \
    o0 = mfma32(pa1, LDSV(vc, 0, 1), o0);                                       \
    o1 = mfma32(pa1, LDSV(vc, 1, 1), o1);                                       \
    o0 = mfma32(pb0, LDSV(vc, 0, 2), o0);                                       \
    o1 = mfma32(pb0, LDSV(vc, 1, 2), o1);                                       \
    o0 = mfma32(pb1, LDSV(vc, 0, 3), o0);                                       \
    o1 = mfma32(pb1, LDSV(vc, 1, 3), o1);                                       \
    __builtin_amdgcn_s_setprio(0);                                              \
  } while (0)

  const f32x16 z16 = {};
  f32x16 o0 = z16, o1 = z16;
  f32x16 sA0, sA1, sB0, sB1;
  bf16x8 pa0, pa1, pb0, pb1;
  float ps0 = 0.f, ps1 = 0.f, ps2 = 0.f, ps3 = 0.f;

  STAGE(0, 0);
  STAGE(1, 64);
  // vmcnt(6): of 8 outstanding (K0,K0,V0,V0,K1,K1,V1,V1), newest 6 remain
  // -> K0 landed. Barrier makes all waves' K0 quarters visible.
  asm volatile("s_waitcnt vmcnt(6)" ::: "memory");
  __builtin_amdgcn_s_barrier();
  __builtin_amdgcn_sched_barrier(0);
  QK(sA0, sA1, Ks[0]);  // tile 0 -> state A

  for (int t = 0; t < 32; t += 2) {
    // ---- step t (even): current = A(tile t), next = B(tile t+1) ----
    if (t < 30) {
      STAGE((t + 2) & 3, (t + 2) * 64);
      // outstanding: tile t+1 (4) + tile t+2 (4); vmcnt(6) leaves
      // [V(t+1)x2, tile(t+2)x4] -> V(t) and K(t+1) landed.
      asm volatile("s_waitcnt vmcnt(6)" ::: "memory");
    } else {
      asm volatile("s_waitcnt vmcnt(2)" ::: "memory");  // V30 + K31 landed
    }
    __builtin_amdgcn_s_barrier();
    __builtin_amdgcn_sched_barrier(0);
    QK(sB0, sB1, Ks[(t + 1) & 3]);   // tile t+1 (matrix pipe, independent)
    SOFTMAX(sA0, sA1);               // tile t (VALU) - overlaps QK above
    PV(Vs[t & 3]);                   // tile t

    // ---- step t+1 (odd): current = B(tile t+1), next = A(tile t+2) ----
    if (t < 29) {
      STAGE((t + 3) & 3, (t + 3) * 64);
      asm volatile("s_waitcnt vmcnt(6)" ::: "memory");
    } else {
      asm volatile("s_waitcnt vmcnt(0)" ::: "memory");  // V31 landed
    }
    __builtin_amdgcn_s_barrier();
    __builtin_amdgcn_sched_barrier(0);
    if (t < 30) QK(sA0, sA1, Ks[(t + 2) & 3]);  // tile t+2
    SOFTMAX(sB0, sB1);
    PV(Vs[(t + 1) & 3]);
  }
#undef STAGE
#undef LDSK
#undef LDSV
#undef QK
#undef SOFTMAX
#undef PV

  // tot on lane l = softmax denominator for q = q0 + (l&31)
  float plsum = (ps0 + ps1) + (ps2 + ps3);
  float tot = plsum + __shfl_xor(plsum, 32);

#pragma unroll
  for (int r = 0; r < 16; ++r) {
    int qr = (r & 3) + 8 * (r >> 2) + 4 * g;        // output row of o0[r]/o1[r]
    float inv = 1.0f / __shfl(tot, qr);             // row qr's denominator
    bf16* op = AO + (size_t)(b * 2048 + q0 + qr) * 1024 + h * 64 + lo5;
    op[0]  = (bf16)(o0[r] * inv);
    op[32] = (bf16)(o1[r] * inv);
  }
}

// ---------------------------------------------------------------------------
// Kernel 4: output projection, 64x128 tile (512 blocks = 2/CU), m97 structure,
// swizzled LDS. fp32 out + bias.
// ---------------------------------------------------------------------------
__global__ __launch_bounds__(256) void gemm_o(
    const bf16* __restrict__ A, const bf16* __restrict__ Wt3,
    const float* __restrict__ bo, float* __restrict__ C) {
  __shared__ bf16 As[2][64 * 32];
  __shared__ bf16 Bs[2][128 * 32];
  int m0 = blockIdx.x * 64, n0 = blockIdx.y * 128;
  int tid = threadIdx.x, w = tid >> 6, l = tid & 63;
  int wm = (w >> 1) * 32, wn = (w & 1) * 64;
  int c16 = l & 15, g = l >> 4;
  int rsw = (c16 >> 1) & 3;

  // A staging: 1 chunk/lane. row = tid>>2, phys chunk = tid&3
  int arow = tid >> 2, akc = tid & 3;
  int asrc = (akc ^ ((arow >> 1) & 3)) * 8;
  // B staging: 2 chunks/lane
  int brow0 = (w * 2 + 0) * 16 + (l >> 2);
  int brow1 = (w * 2 + 1) * 16 + (l >> 2);
  int bk0 = ((l & 3) ^ ((brow0 >> 1) & 3)) * 8;
  int bk1 = ((l & 3) ^ ((brow1 >> 1) & 3)) * 8;

  f32x4 acc[2][4] = {};

#define STAGE_O(buf, kt)                                                     \
  do {                                                                       \
    gload_lds16(A + (size_t)(m0 + arow) * 1024 + (kt) + asrc,                \
                (char*)As[buf] + tid * 16);                                  \
    gload_lds16(Wt3 + (size_t)(n0 + brow0) * 1024 + (kt) + bk0,              \
                (char*)Bs[buf] + (w * 2 + 0) * 1024 + l * 16);               \
    gload_lds16(Wt3 + (size_t)(n0 + brow1) * 1024 + (kt) + bk1,              \
                (char*)Bs[buf] + (w * 2 + 1) * 1024 + l * 16);               \
  } while (0)

  STAGE_O(0, 0);
  __syncthreads();

  int cur = 0;
  for (int kt = 0; kt < 1024; kt += 32) {
    if (kt < 992) STAGE_O(cur ^ 1, kt + 32);
    bf16x8 af[2], bfr[4];
#pragma unroll
    for (int mt = 0; mt < 2; ++mt)
      af[mt] = *(const bf16x8*)&As[cur][(wm + mt * 16 + c16) * 32 + ((g ^ rsw) * 8)];
#pragma unroll
    for (int nt = 0; nt < 4; ++nt)
      bfr[nt] = *(const bf16x8*)&Bs[cur][(wn + nt * 16 + c16) * 32 + ((g ^ rsw) * 8)];
#pragma unroll
    for (int mt = 0; mt < 2; ++mt)
#pragma unroll
      for (int nt = 0; nt < 4; ++nt)
        acc[mt][nt] = mfma16(af[mt], bfr[nt], acc[mt][nt]);
    __syncthreads();  // drains vmcnt -> next buffer staged
    cur ^= 1;
  }
#undef STAGE_O

#pragma unroll
  for (int mt = 0; mt < 2; ++mt)
#pragma unroll
    for (int nt = 0; nt < 4; ++nt) {
      int n = n0 + wn + nt * 16 + c16;
      float bb = bo[n];
#pragma unroll
      for (int r = 0; r < 4; ++r) {
        int m = m0 + wm + mt * 16 + g * 4 + r;
        C[(size_t)m * 1024 + n] = acc[mt][nt][r] + bb;
      }
    }
}

// ---------------------------------------------------------------------------
extern "C" void kernel_launch(void* const* d_in, const int* in_sizes, int n_in,
                              void* d_out, int out_size, void* d_ws, size_t ws_size,
                              hipStream_t stream) {
  const float* query = (const float*)d_in[0];
  const float* key_  = (const float*)d_in[1];
  const float* value = (const float*)d_in[2];
  const float* Wq = (const float*)d_in[3];
  const float* bq = (const float*)d_in[4];
  const float* Wk = (const float*)d_in[5];
  const float* bk = (const float*)d_in[6];
  const float* Wv = (const float*)d_in[7];
  const float* bv = (const float*)d_in[8];
  const float* Wo = (const float*)d_in[9];
  const float* bo = (const float*)d_in[10];
  float* out = (float*)d_out;

  char* ws = (char*)d_ws;
  const size_t MB = 1024 * 1024;
  bf16* Wt  = (bf16*)(ws);              // 4 x [1024][1024] bf16 = 8 MB
  bf16* Qp  = (bf16*)(ws + 8 * MB);     // [4096][1024] bf16 (pre-scaled)
  bf16* Kp  = (bf16*)(ws + 16 * MB);    // [4096][1024]
  bf16* Vt  = (bf16*)(ws + 24 * MB);    // [32][64][2048]
  bf16* AO  = (bf16*)(ws + 32 * MB);    // attn out [4096][1024]

  wt_kernel<<<dim3(256, 4), dim3(256), 0, stream>>>(Wq, Wk, Wv, Wo, Wt);
  gemm_qkv<<<dim3(32, 8, 3), dim3(256), 0, stream>>>(query, key_, value, Wt,
                                                     bq, bk, bv, Qp, Kp, Vt);
  flash_kernel<<<dim3(512), dim3(256), 0, stream>>>(Qp, Kp, Vt, AO);
  gemm_o<<<dim3(64, 8), dim3(256), 0, stream>>>(AO, Wt + (size_t)3 * 1024 * 1024, bo, out);
}